// Round 3
// baseline (719.829 us; speedup 1.0000x reference)
//
#include <hip/hip_runtime.h>
#include <hip/hip_bf16.h>
#include <stdint.h>

// Problem constants
#define MM   32768   // B*S
#define FFD  1024    // F
#define NQKV 3072    // 3*F

typedef __bf16 bf16x8 __attribute__((ext_vector_type(8)));
typedef float  f32x4  __attribute__((ext_vector_type(4)));

__device__ __forceinline__ unsigned short f2bf_bits(float f){
  __hip_bfloat16 h = __float2bfloat16(f);
  unsigned short u;
  __builtin_memcpy(&u, &h, 2);
  return u;
}

__device__ __forceinline__ void gld16(const void* g, void* l){
  const unsigned int* gu = (const unsigned int*)g;
  unsigned int* lu = (unsigned int*)l;
  __builtin_amdgcn_global_load_lds(
      (const __attribute__((address_space(1))) unsigned int*)gu,
      (__attribute__((address_space(3))) unsigned int*)lu,
      16, 0, 0);
}

// ---------- convert fp32 -> bf16, 4 elems/thread ----------
__global__ __launch_bounds__(256) void k_convert_bf16(const float* __restrict__ in,
                                                      unsigned short* __restrict__ out,
                                                      int n4){
  int i = blockIdx.x * 256 + threadIdx.x;
  if (i >= n4) return;
  float4 v = ((const float4*)in)[i];
  ushort4 r;
  r.x = f2bf_bits(v.x); r.y = f2bf_bits(v.y);
  r.z = f2bf_bits(v.z); r.w = f2bf_bits(v.w);
  ((ushort4*)out)[i] = r;
}

// ---------- 4 fused transpose-converts: out(N x K bf16) = in(K x N fp32)^T ----------
__global__ __launch_bounds__(256) void k_transpose4(
    const float* __restrict__ W0, const float* __restrict__ W1,
    const float* __restrict__ W2, const float* __restrict__ W3,
    unsigned short* __restrict__ D0, unsigned short* __restrict__ D1,
    unsigned short* __restrict__ D2, unsigned short* __restrict__ D3){
  __shared__ float tile[32][33];
  const float* in;
  unsigned short* out;
  switch (blockIdx.z){
    case 0:  in = W0; out = D0; break;
    case 1:  in = W1; out = D1; break;
    case 2:  in = W2; out = D2; break;
    default: in = W3; out = D3; break;
  }
  int bc = blockIdx.x * 32, br = blockIdx.y * 32;
  int tx = threadIdx.x, ty = threadIdx.y;
  #pragma unroll
  for (int j = 0; j < 32; j += 8)
    tile[ty + j][tx] = in[(size_t)(br + ty + j) * 1024 + bc + tx];
  __syncthreads();
  #pragma unroll
  for (int j = 0; j < 32; j += 8)
    out[(size_t)(bc + ty + j) * 1024 + br + tx] = f2bf_bits(tile[tx][ty + j]);
}

// ---------- bf16 MFMA GEMM1: C(MxN) = A(MxK) * Bt(NxK)^T + bias -> bf16 ----------
// 128x128 block tile, 256 threads (4 waves in 2x2), 16x16x32 MFMA, BK=64.
__global__ __launch_bounds__(256) void k_gemm_bt(
    const unsigned short* __restrict__ A,
    const unsigned short* __restrict__ Bt,
    const float* __restrict__ b0, const float* __restrict__ b1, const float* __restrict__ b2,
    unsigned short* __restrict__ Cout, int M, int N, int K)
{
  __shared__ unsigned short As[128 * 64];
  __shared__ unsigned short Bs[128 * 64];

  const int tid  = threadIdx.x;
  const int lane = tid & 63;
  const int wave = tid >> 6;
  const int wr = wave >> 1, wc = wave & 1;
  const int quad = lane >> 4, lrow = lane & 15;

  const long rowBase = (long)blockIdx.y * 128;
  const long colBase = (long)blockIdx.x * 128;

  f32x4 acc[4][4];
  #pragma unroll
  for (int i = 0; i < 4; i++)
    #pragma unroll
    for (int j = 0; j < 4; j++)
      acc[i][j] = (f32x4){0.f, 0.f, 0.f, 0.f};

  const unsigned short* ga = A  + (rowBase + (tid >> 2)) * (long)K + (tid & 3) * 8;
  const unsigned short* gb = Bt + (colBase + (tid >> 2)) * (long)K + (tid & 3) * 8;
  unsigned short* la = As + tid * 8;
  unsigned short* lb = Bs + tid * 8;
  const long rstep = 64L * K;

  const int nk = K >> 6;
  for (int kt = 0; kt < nk; kt++){
    __syncthreads();
    gld16(ga,               la);
    gld16(ga + rstep,       la + 2048);
    gld16(ga + 32,          la + 4096);
    gld16(ga + 32 + rstep,  la + 6144);
    gld16(gb,               lb);
    gld16(gb + rstep,       lb + 2048);
    gld16(gb + 32,          lb + 4096);
    gld16(gb + 32 + rstep,  lb + 6144);
    __syncthreads();

    #pragma unroll
    for (int kk = 0; kk < 2; kk++){
      const unsigned short* Ah = As + kk * 4096;
      const unsigned short* Bh = Bs + kk * 4096;
      bf16x8 af[4], bfr[4];
      #pragma unroll
      for (int i = 0; i < 4; i++)
        af[i]  = *(const bf16x8*)(Ah + (wr * 64 + i * 16 + lrow) * 32 + quad * 8);
      #pragma unroll
      for (int j = 0; j < 4; j++)
        bfr[j] = *(const bf16x8*)(Bh + (wc * 64 + j * 16 + lrow) * 32 + quad * 8);

      #pragma unroll
      for (int i = 0; i < 4; i++)
        #pragma unroll
        for (int j = 0; j < 4; j++)
          acc[i][j] = __builtin_amdgcn_mfma_f32_16x16x32_bf16(af[i], bfr[j], acc[i][j], 0, 0, 0);
    }

    ga += 64; gb += 64;
  }

  #pragma unroll
  for (int j = 0; j < 4; j++){
    long col = colBase + wc * 64 + j * 16 + lrow;
    const float* bp = (col < 1024) ? b0 : ((col < 2048) ? b1 : b2);
    float bias = bp[col & 1023];
    #pragma unroll
    for (int i = 0; i < 4; i++){
      long row0 = rowBase + wr * 64 + i * 16 + quad * 4;
      #pragma unroll
      for (int r = 0; r < 4; r++){
        float v = acc[i][j][r] + bias;
        Cout[(row0 + r) * (long)N + col] = f2bf_bits(v);
      }
    }
  }
}

// ---------- GEMM2 + bias + LayerNorm fused ----------
// C(64 x 1024) = A(64 x 1024) @ Wo + bo, then LN over the 1024-wide rows.
// Block: 512 threads = 8 waves; wave w covers cols [w*128, w*128+128).
// LDS: Bs 1024x32 bf16 (64KB, whole Wo^T k-slice), As 64x32 bf16 (4KB).
__global__ __launch_bounds__(512) void k_gemm2_ln(
    const unsigned short* __restrict__ A,     // 32768 x 1024 bf16
    const unsigned short* __restrict__ Bt,    // 1024 x 1024 bf16 (Wo^T)
    const float* __restrict__ bo,
    const float* __restrict__ gamma,
    const float* __restrict__ beta,
    float* __restrict__ out)
{
  __shared__ unsigned short Bs[1024 * 32];
  __shared__ unsigned short As[64 * 32];
  __shared__ float redS[64 * 8];
  __shared__ float redQ[64 * 8];
  __shared__ float redM[64];
  __shared__ float redR[64];

  const int tid  = threadIdx.x;
  const int lane = tid & 63;
  const int wave = tid >> 6;                // 0..7
  const int quad = lane >> 4, lidx = lane & 15;
  const long rowBase = (long)blockIdx.x * 64;
  const int K = 1024;

  f32x4 acc[4][8];
  #pragma unroll
  for (int i = 0; i < 4; i++)
    #pragma unroll
    for (int j = 0; j < 8; j++)
      acc[i][j] = (f32x4){0.f, 0.f, 0.f, 0.f};

  const unsigned short* gb = Bt + (tid >> 2) * (long)K + (tid & 3) * 8;
  unsigned short* lb = Bs + tid * 8;
  const unsigned short* ga = A + (rowBase + (tid >> 2)) * (long)K + (tid & 3) * 8; // tid<256 only
  unsigned short* la = As + tid * 8;

  for (int kt = 0; kt < 32; kt++){
    __syncthreads();
    #pragma unroll
    for (int i = 0; i < 8; i++)
      gld16(gb + i * (128L * K), lb + i * 4096);
    if (tid < 256) gld16(ga, la);
    __syncthreads();

    bf16x8 af[4], bfr[8];
    #pragma unroll
    for (int i = 0; i < 4; i++)
      af[i] = *(const bf16x8*)(As + (i * 16 + lidx) * 32 + quad * 8);
    #pragma unroll
    for (int j = 0; j < 8; j++)
      bfr[j] = *(const bf16x8*)(Bs + (wave * 128 + j * 16 + lidx) * 32 + quad * 8);

    #pragma unroll
    for (int i = 0; i < 4; i++)
      #pragma unroll
      for (int j = 0; j < 8; j++)
        acc[i][j] = __builtin_amdgcn_mfma_f32_16x16x32_bf16(af[i], bfr[j], acc[i][j], 0, 0, 0);

    gb += 32; ga += 32;
  }

  // epilogue: bias add, row stats, LN, store.
  // lane holds rows i*16 + quad*4 + r (i in 0..3, r in 0..3), cols wave*128 + j*16 + lidx.
  float bias[8], gmm[8], btt[8];
  #pragma unroll
  for (int j = 0; j < 8; j++){
    int col = wave * 128 + j * 16 + lidx;
    bias[j] = bo[col]; gmm[j] = gamma[col]; btt[j] = beta[col];
  }

  float s1[4][4], s2[4][4];
  #pragma unroll
  for (int i = 0; i < 4; i++)
    #pragma unroll
    for (int r = 0; r < 4; r++){ s1[i][r] = 0.f; s2[i][r] = 0.f; }

  #pragma unroll
  for (int i = 0; i < 4; i++)
    #pragma unroll
    for (int j = 0; j < 8; j++)
      #pragma unroll
      for (int r = 0; r < 4; r++){
        float v = acc[i][j][r] + bias[j];
        acc[i][j][r] = v;
        s1[i][r] += v;
        s2[i][r] += v * v;
      }

  // reduce across the 16 lidx lanes (same row)
  #pragma unroll
  for (int off = 1; off < 16; off <<= 1){
    #pragma unroll
    for (int i = 0; i < 4; i++)
      #pragma unroll
      for (int r = 0; r < 4; r++){
        s1[i][r] += __shfl_xor(s1[i][r], off);
        s2[i][r] += __shfl_xor(s2[i][r], off);
      }
  }
  if (lidx == 0){
    #pragma unroll
    for (int i = 0; i < 4; i++)
      #pragma unroll
      for (int r = 0; r < 4; r++){
        int row = i * 16 + quad * 4 + r;
        redS[row * 8 + wave] = s1[i][r];
        redQ[row * 8 + wave] = s2[i][r];
      }
  }
  __syncthreads();
  if (tid < 64){
    float S = 0.f, Q = 0.f;
    #pragma unroll
    for (int w = 0; w < 8; w++){ S += redS[tid * 8 + w]; Q += redQ[tid * 8 + w]; }
    float mean = S * (1.0f / 1024.0f);
    float var  = Q * (1.0f / 1024.0f) - mean * mean;
    redM[tid] = mean;
    redR[tid] = rsqrtf(var + 1e-5f);
  }
  __syncthreads();

  #pragma unroll
  for (int i = 0; i < 4; i++)
    #pragma unroll
    for (int r = 0; r < 4; r++){
      int row = i * 16 + quad * 4 + r;
      float mean = redM[row], rstd = redR[row];
      float* orow = out + (rowBase + row) * 1024L + wave * 128;
      #pragma unroll
      for (int j = 0; j < 8; j++)
        orow[j * 16 + lidx] = (acc[i][j][r] - mean) * rstd * gmm[j] + btt[j];
    }
}

// ---------- per-position head-attention via MFMA ----------
__global__ __launch_bounds__(256) void k_attention(const unsigned short* __restrict__ qkv,
                                                   unsigned short* __restrict__ aout){
  constexpr int QOFF = 0;            // [16][72] = 1152
  constexpr int KOFF = 1152;         // [16][72] = 1152
  constexpr int VOFF = 2304;         // [64][40] = 2560
  constexpr int POFF = 4864;         // [16][40] = 640
  constexpr int PER  = 5504;
  __shared__ unsigned short smem[4 * PER];

  const int lane = threadIdx.x & 63;
  const int wave = threadIdx.x >> 6;
  const int pos  = blockIdx.x * 4 + wave;
  const int quad = lane >> 4, lidx = lane & 15;

  unsigned short* base = smem + wave * PER;
  unsigned short* Qb = base + QOFF;
  unsigned short* Kb = base + KOFF;
  unsigned short* Vt = base + VOFF;
  unsigned short* Pb = base + POFF;

  {
    uint4 z = {0u, 0u, 0u, 0u};
    *(uint4*)(Vt + lane * 40 + 16) = z;
    *(uint4*)(Vt + lane * 40 + 24) = z;
    *(uint2*)(Pb + (lane >> 2) * 40 + 16 + (lane & 3) * 4) = make_uint2(0u, 0u);
  }

  const unsigned short* src = qkv + (size_t)pos * 3072;
  #pragma unroll
  for (int i = 0; i < 6; i++){
    int c = i * 64 + lane;
    uint4 u = *(const uint4*)(src + c * 8);
    if (i < 4){
      unsigned short* mb = (c < 128) ? Qb : Kb;
      int cc = c & 127;
      *(uint4*)(mb + (cc >> 3) * 72 + (cc & 7) * 8) = u;
    } else {
      int cv = c - 256;
      int g = cv >> 3, d0 = (cv & 7) * 8;
      const unsigned short* us = (const unsigned short*)&u;
      #pragma unroll
      for (int t = 0; t < 8; t++) Vt[(d0 + t) * 40 + g] = us[t];
    }
  }
  __syncthreads();

  f32x4 s = (f32x4){0.f, 0.f, 0.f, 0.f};
  #pragma unroll
  for (int kk = 0; kk < 2; kk++){
    bf16x8 a = *(const bf16x8*)(Qb + lidx * 72 + kk * 32 + quad * 8);
    bf16x8 b = *(const bf16x8*)(Kb + lidx * 72 + kk * 32 + quad * 8);
    s = __builtin_amdgcn_mfma_f32_16x16x32_bf16(a, b, s, 0, 0, 0);
  }

  #pragma unroll
  for (int r = 0; r < 4; r++){
    float v = s[r] * 0.125f;
    float m = v;
    m = fmaxf(m, __shfl_xor(m, 1));
    m = fmaxf(m, __shfl_xor(m, 2));
    m = fmaxf(m, __shfl_xor(m, 4));
    m = fmaxf(m, __shfl_xor(m, 8));
    float e = __expf(v - m);
    float sum = e;
    sum += __shfl_xor(sum, 1);
    sum += __shfl_xor(sum, 2);
    sum += __shfl_xor(sum, 4);
    sum += __shfl_xor(sum, 8);
    float p = e / sum;
    Pb[(quad * 4 + r) * 40 + lidx] = f2bf_bits(p);
  }
  __syncthreads();

  f32x4 o[4];
  #pragma unroll
  for (int n4 = 0; n4 < 4; n4++){
    bf16x8 a = *(const bf16x8*)(Pb + lidx * 40 + quad * 8);
    bf16x8 b = *(const bf16x8*)(Vt + (n4 * 16 + lidx) * 40 + quad * 8);
    o[n4] = __builtin_amdgcn_mfma_f32_16x16x32_bf16(a, b, (f32x4){0.f,0.f,0.f,0.f}, 0, 0, 0);
  }

  #pragma unroll
  for (int n4 = 0; n4 < 4; n4++)
    #pragma unroll
    for (int r = 0; r < 4; r++)
      Qb[(quad * 4 + r) * 72 + n4 * 16 + lidx] = f2bf_bits(o[n4][r]);
  __syncthreads();

  unsigned short* dst = aout + (size_t)pos * 1024;
  #pragma unroll
  for (int t = 0; t < 2; t++){
    int j = lane * 2 + t;
    int h = j >> 3, dc = j & 7;
    uint4 u = *(const uint4*)(Qb + h * 72 + dc * 8);
    *(uint4*)(dst + j * 8) = u;
  }
}

extern "C" void kernel_launch(void* const* d_in, const int* in_sizes, int n_in,
                              void* d_out, int out_size, void* d_ws, size_t ws_size,
                              hipStream_t stream){
  const float* x     = (const float*)d_in[0];
  const float* Wq    = (const float*)d_in[1];
  const float* bq    = (const float*)d_in[2];
  const float* Wk    = (const float*)d_in[3];
  const float* bk    = (const float*)d_in[4];
  const float* Wv    = (const float*)d_in[5];
  const float* bv    = (const float*)d_in[6];
  const float* Wo    = (const float*)d_in[7];
  const float* bo    = (const float*)d_in[8];
  const float* gamma = (const float*)d_in[9];
  const float* beta  = (const float*)d_in[10];
  float* out = (float*)d_out;

  // workspace layout (bytes):
  //   [0, 6291456)            Wqkv^T bf16 (3072 x 1024)
  //   [6291456, 8388608)      Wo^T bf16  (1024 x 1024)
  //   [8388608, 75497472)     xb bf16 (32768 x 1024); reused as attn-out after GEMM1
  //   [75497472, 276824064)   qkv bf16 (32768 x 3072)
  char* ws = (char*)d_ws;
  unsigned short* Wqkv_t = (unsigned short*)ws;
  unsigned short* Wo_t   = (unsigned short*)(ws + 6291456);
  unsigned short* xb     = (unsigned short*)(ws + 8388608);
  unsigned short* qkv    = (unsigned short*)(ws + 75497472);
  unsigned short* aout   = xb;

  // 1) x -> bf16
  k_convert_bf16<<<32768, 256, 0, stream>>>(x, xb, (MM * FFD) / 4);

  // 2) all 4 weight transposes in one launch
  k_transpose4<<<dim3(32, 32, 4), dim3(32, 8), 0, stream>>>(
      Wq, Wk, Wv, Wo,
      Wqkv_t, Wqkv_t + 1024 * 1024, Wqkv_t + 2048 * 1024, Wo_t);

  // 3) QKV GEMM: (32768 x 1024) @ (1024 x 3072) -> bf16
  k_gemm_bt<<<dim3(NQKV / 128, MM / 128), 256, 0, stream>>>(
      xb, Wqkv_t, bq, bk, bv, qkv, MM, NQKV, FFD);

  // 4) per-position head attention (MFMA)
  k_attention<<<MM / 4, 256, 0, stream>>>(qkv, aout);

  // 5) output GEMM + bias + LayerNorm fused -> fp32 d_out
  k_gemm2_ln<<<MM / 64, 512, 0, stream>>>(aout, Wo_t, bo, gamma, beta, out);
}